// Round 5
// baseline (1322.162 us; speedup 1.0000x reference)
//
#include <hip/hip_runtime.h>

typedef unsigned int uint;
typedef unsigned short ushort;
typedef __attribute__((ext_vector_type(8))) short b16x8;
typedef __attribute__((ext_vector_type(4))) float f32x4;

// ws byte offsets
#define PHIUT_OFF 0u
#define SQLP_OFF  524288u
#define SMU_OFF   (524288u + 65536u)
#define WBUF_OFF  (524288u + 131072u)
#define KLSO_OFF  (524288u + 131072u + 1048576u)

__device__ __forceinline__ ushort f2bf(float x){
  union { float f; uint u; } v; v.f = x;
  uint r = v.u + 0x7fffu + ((v.u >> 16) & 1u);
  return (ushort)(r >> 16);
}
__device__ __forceinline__ float bflo(uint u){ union { uint uu; float f; } v; v.uu = u << 16; return v.f; }
__device__ __forceinline__ float bfhi(uint u){ union { uint uu; float f; } v; v.uu = u & 0xffff0000u; return v.f; }
__device__ __forceinline__ uint pk2(float a, float b){ return (uint)f2bf(a) | ((uint)f2bf(b) << 16); }

// C = A_rows · B_rows^T (NT), 128x128x128, bf16 MFMA 16x16x32.
__device__ __forceinline__ void mfma128(const ushort (*A)[136], const ushort (*B)[136],
                                        f32x4 acc[2][8], int wv, int lane){
  const int lr = lane & 15, lk = lane >> 4;
  #pragma unroll
  for (int ti = 0; ti < 2; ++ti)
    #pragma unroll
    for (int tj = 0; tj < 8; ++tj)
      acc[ti][tj] = (f32x4){0.f, 0.f, 0.f, 0.f};
  #pragma unroll
  for (int kk = 0; kk < 4; ++kk){
    const int kof = kk * 32 + lk * 8;
    b16x8 a0 = *(const b16x8*)&A[(wv * 2 + 0) * 16 + lr][kof];
    b16x8 a1 = *(const b16x8*)&A[(wv * 2 + 1) * 16 + lr][kof];
    #pragma unroll
    for (int tj = 0; tj < 8; ++tj){
      b16x8 bf = *(const b16x8*)&B[tj * 16 + lr][kof];
      acc[0][tj] = __builtin_amdgcn_mfma_f32_16x16x32_bf16(a0, bf, acc[0][tj], 0, 0, 0);
      acc[1][tj] = __builtin_amdgcn_mfma_f32_16x16x32_bf16(a1, bf, acc[1][tj], 0, 0, 0);
    }
  }
}

// ---------------- K0: prep (phiU^T bf16, exp(lp/2), exp(lp/2)*mu) ----------------
__global__ void k0_prep(const float* __restrict__ U, const float* __restrict__ mu,
                        const float* __restrict__ lp, ushort* __restrict__ phiUT,
                        float* __restrict__ sqlp, float* __restrict__ smu)
{
  __shared__ __align__(16) ushort T0[128][132];
  const int tid = threadIdx.x;
  const int bid = blockIdx.x;
  if (bid < 16){
    const float* Us = U + ((size_t)bid << 14);
    for (int e = tid * 4; e < 16384; e += 1024){
      f32x4 v = *(const f32x4*)&Us[e];
      int m = e >> 7, d = e & 127;
      uint2 pv; pv.x = pk2(fmaxf(v[0],0.f), fmaxf(v[1],0.f));
      pv.y = pk2(fmaxf(v[2],0.f), fmaxf(v[3],0.f));
      *(uint2*)&T0[m][d] = pv;
    }
    __syncthreads();
    ushort* op = phiUT + ((size_t)bid << 14);
    for (int e = tid; e < 16384; e += 256){
      int d = e >> 7, m2 = e & 127;
      op[e] = T0[m2][d];
    }
  } else {
    int idx = ((bid - 16) << 8) + tid;
    float l = lp[idx], m = mu[idx];
    float ex = expf(0.5f * l);
    sqlp[idx] = ex;
    smu[idx]  = ex * m;
  }
}

// ===== macro machinery for the static in-register 128x32 panel LDL =====
#define SH4(D, S, L) D[0]=__shfl(S[0],(L)); D[1]=__shfl(S[1],(L)); D[2]=__shfl(S[2],(L)); D[3]=__shfl(S[3],(L));

#define BC7(T) SH4(bv7, ya7, T)
#define BC6(T) SH4(bv6, ya6, T) BC7(T)
#define BC5(T) SH4(bv5, ya5, T) BC6(T)
#define BC4(T) SH4(bv4, ya4, T) BC5(T)
#define BC3(T) SH4(bv3, ya3, T) BC4(T)
#define BC2(T) SH4(bv2, ya2, T) BC3(T)
#define BC1(T) SH4(bv1, ya1, T) BC2(T)
#define BC0(T) SH4(bv0, ya0, T) BC1(T)

#define UP7(M0,M1) ya7 -= (M0)*bv7; yb7 -= (M1)*bv7;
#define UP6(M0,M1) ya6 -= (M0)*bv6; yb6 -= (M1)*bv6; UP7(M0,M1)
#define UP5(M0,M1) ya5 -= (M0)*bv5; yb5 -= (M1)*bv5; UP6(M0,M1)
#define UP4(M0,M1) ya4 -= (M0)*bv4; yb4 -= (M1)*bv4; UP5(M0,M1)
#define UP3(M0,M1) ya3 -= (M0)*bv3; yb3 -= (M1)*bv3; UP4(M0,M1)
#define UP2(M0,M1) ya2 -= (M0)*bv2; yb2 -= (M1)*bv2; UP3(M0,M1)
#define UP1(M0,M1) ya1 -= (M0)*bv1; yb1 -= (M1)*bv1; UP2(M0,M1)
#define UP0(M0,M1) ya0 -= (M0)*bv0; yb0 -= (M1)*bv0; UP1(M0,M1)

#define MSK0(V)
#define MSK1(V) V[0]=0.f;
#define MSK2(V) V[0]=0.f; V[1]=0.f;
#define MSK3(V) V[0]=0.f; V[1]=0.f; V[2]=0.f;

// One LDL pivot step, all indices compile-time. Uniform rank-1 update:
// finished rows/cols self-zero, so updating the full tail j4>=T4 is exact.
#define STEP(T, T4, TQ, BCM, UPM, MSKM) { \
  BCM(T) \
  float dpv_ = bv##T4[TQ]; \
  if (lane == (T)) dvec[k0 + (T)] = dpv_; \
  float rk_ = 1.0f / dpv_; \
  MSKM(bv##T4) \
  float m0_ = ya##T4[TQ] * rk_; \
  float m1_ = yb##T4[TQ] * rk_; \
  UPM(m0_, m1_) \
  ya##T4[TQ] = m0_; \
  yb##T4[TQ] = m1_; \
}

#define LD(J) ya##J = h0 ? *(f32x4*)&Bm[r0][k0 + 4*(J)] : z4; \
              yb##J = h1 ? *(f32x4*)&Bm[r1][k0 + 4*(J)] : z4;
#define ST(J) if (h0) *(f32x4*)&Bm[r0][k0 + 4*(J)] = ya##J; \
              if (h1) *(f32x4*)&Bm[r1][k0 + 4*(J)] = yb##J;

// bf16 operand writeback (PA = -L*D rows 0..31, PB = L rows 32..63, cols 68..131)
#define WPQ(ROW, Y0, Y1, Q) { \
  f32x4 d0_ = *(const f32x4*)&dvec[k0 + (Q)*8]; \
  f32x4 d1_ = *(const f32x4*)&dvec[k0 + (Q)*8 + 4]; \
  f32x4 a0_ = (f32x4){0.f,0.f,0.f,0.f} - Y0 * d0_; \
  f32x4 a1_ = (f32x4){0.f,0.f,0.f,0.f} - Y1 * d1_; \
  uint4 ua_, ub_; \
  ua_.x = pk2(a0_[0],a0_[1]); ua_.y = pk2(a0_[2],a0_[3]); \
  ua_.z = pk2(a1_[0],a1_[1]); ua_.w = pk2(a1_[2],a1_[3]); \
  ub_.x = pk2(Y0[0],Y0[1]);   ub_.y = pk2(Y0[2],Y0[3]); \
  ub_.z = pk2(Y1[0],Y1[1]);   ub_.w = pk2(Y1[2],Y1[3]); \
  int fidx_ = (ROW)*16 + (Q)*4; \
  *(uint4*)&Bm[fidx_ >> 6][68 + (fidx_ & 63)] = ua_; \
  *(uint4*)&Bm[32 + (fidx_ >> 6)][68 + (fidx_ & 63)] = ub_; }
#define WPROW(ROW, V0,V1,V2,V3,V4,V5,V6,V7) \
  WPQ(ROW, V0, V1, 0) WPQ(ROW, V2, V3, 1) WPQ(ROW, V4, V5, 2) WPQ(ROW, V6, V7, 3)

// ---------------- K2: per-(s,o) factorization ----------------
// Reversed space: B = J A J = Wt·Wt^T + I. LDL: B = L~ D L~^T ; S = L~^{-1}.
// logdet_prec = Σ log d_k ; tr(q_cov) = Σ_i ||S row i||²/d_i
// p = S v~ ; qmu~ = S^T (p/d) ; w~ = qmu~ + S^T (eps~/√d) ; w[d] = w~[127-d]
__global__ __launch_bounds__(256, 2) void k2_factor(
    const ushort* __restrict__ phiUT, const float* __restrict__ sqlp,
    const float* __restrict__ smu, const float* __restrict__ eps,
    float* __restrict__ wout, float* __restrict__ klso)
{
  __shared__ __align__(16) float Bm[128][132];
  __shared__ __align__(16) float Tscr[4][2][16][16];
  __shared__ __align__(16) float svec[128];
  __shared__ __align__(16) float smuv[128];
  __shared__ __align__(16) float epsv[128];
  __shared__ __align__(16) float utlv[128];
  __shared__ __align__(16) float dvec[128];
  __shared__ __align__(16) float pvec[128];
  __shared__ __align__(16) float qmuv[128];
  __shared__ __align__(16) float wtv[128];
  float* trv = smuv;   // smuv dead after phase 3
  float* red = svec;   // svec dead after phase 2
  ushort (*Wt)[136] = (ushort (*)[136])&Bm[0][0];

  const int tid  = threadIdx.x;
  const int lane = tid & 63;
  const int wv   = tid >> 6;
  const int s    = blockIdx.x >> 7;
  const int o    = blockIdx.x & 127;

  // phase 1: vectors
  if (tid < 128){
    svec[tid] = sqlp[(o << 7) + tid];
    epsv[tid] = eps[(((size_t)s * 128 + o) << 7) + 127 - tid];
  } else {
    int t2 = tid - 128;
    smuv[t2] = smu[(o << 7) + t2];
  }
  __syncthreads();

  // phase 2: Wt fill (reversed rows, scaled, bf16)
  for (int e = tid * 8; e < 16384; e += 2048){
    int dp = e >> 7, m = e & 127;
    const ushort* srcp = phiUT + (((size_t)s) << 14) + ((size_t)(127 - dp) << 7) + m;
    uint4 raw = *(const uint4*)srcp;
    f32x4 c0 = *(f32x4*)&svec[m];
    f32x4 c1 = *(f32x4*)&svec[m + 4];
    uint4 ov;
    ov.x = pk2(bflo(raw.x)*c0[0], bfhi(raw.x)*c0[1]);
    ov.y = pk2(bflo(raw.y)*c0[2], bfhi(raw.y)*c0[3]);
    ov.z = pk2(bflo(raw.z)*c1[0], bfhi(raw.z)*c1[1]);
    ov.w = pk2(bflo(raw.w)*c1[2], bfhi(raw.w)*c1[3]);
    *(uint4*)&Wt[dp][m] = ov;
  }
  __syncthreads();

  // phase 3: v~ = Wt · (sqrtLp ⊙ mu)
  if (tid < 128){
    float acc3 = 0.f;
    for (int m = 0; m < 128; m += 8){
      uint4 raw = *(uint4*)&Wt[tid][m];
      f32x4 u0 = *(f32x4*)&smuv[m];
      f32x4 u1 = *(f32x4*)&smuv[m + 4];
      acc3 += bflo(raw.x) * u0[0] + bfhi(raw.x) * u0[1]
            + bflo(raw.y) * u0[2] + bfhi(raw.y) * u0[3]
            + bflo(raw.z) * u1[0] + bfhi(raw.z) * u1[1]
            + bflo(raw.w) * u1[2] + bfhi(raw.w) * u1[3];
    }
    utlv[tid] = acc3;
  }
  __syncthreads();

  // phase 4: MFMA Gram
  f32x4 acc[2][8];
  mfma128(Wt, Wt, acc, wv, lane);
  __syncthreads();  // Wt reads complete before overwrite

  // phase 5: Bm = Gram + I (full matrix)
  {
    const int lr = lane & 15, lk = lane >> 4;
    #pragma unroll
    for (int ti = 0; ti < 2; ++ti){
      #pragma unroll
      for (int tj = 0; tj < 8; ++tj){
        int c = tj * 16 + lr;
        #pragma unroll
        for (int q = 0; q < 4; ++q){
          int r = (wv * 2 + ti) * 16 + lk * 4 + q;
          float v = acc[ti][tj][q];
          if (r == c) v += 1.0f;
          Bm[r][c] = v;
        }
      }
    }
  }
  __syncthreads();

  // phase 6: blocked LDL, panel width 32. wave0 factors the 128x32 panel in
  // STATIC registers (named f32x4 vars, macro-unrolled 32 steps, readlane
  // broadcasts); all waves apply MFMA bf16 trailing update, including the
  // super-diagonal 16x16 band tiles at every future panel boundary.
  for (int p = 0; p < 4; ++p){
    const int k0 = p << 5;
    const int nrows = 128 - k0;
    if (wv == 0){
      const int r0 = k0 + lane, r1 = k0 + 64 + lane;
      const bool h0 = lane < nrows;
      const bool h1 = (64 + lane) < nrows;
      const f32x4 z4 = (f32x4){0.f,0.f,0.f,0.f};
      f32x4 ya0,ya1,ya2,ya3,ya4,ya5,ya6,ya7;
      f32x4 yb0,yb1,yb2,yb3,yb4,yb5,yb6,yb7;
      f32x4 bv0=z4,bv1=z4,bv2=z4,bv3=z4,bv4=z4,bv5=z4,bv6=z4,bv7=z4;
      LD(0) LD(1) LD(2) LD(3) LD(4) LD(5) LD(6) LD(7)

      STEP( 0,0,0,BC0,UP0,MSK0) STEP( 1,0,1,BC0,UP0,MSK1) STEP( 2,0,2,BC0,UP0,MSK2) STEP( 3,0,3,BC0,UP0,MSK3)
      STEP( 4,1,0,BC1,UP1,MSK0) STEP( 5,1,1,BC1,UP1,MSK1) STEP( 6,1,2,BC1,UP1,MSK2) STEP( 7,1,3,BC1,UP1,MSK3)
      STEP( 8,2,0,BC2,UP2,MSK0) STEP( 9,2,1,BC2,UP2,MSK1) STEP(10,2,2,BC2,UP2,MSK2) STEP(11,2,3,BC2,UP2,MSK3)
      STEP(12,3,0,BC3,UP3,MSK0) STEP(13,3,1,BC3,UP3,MSK1) STEP(14,3,2,BC3,UP3,MSK2) STEP(15,3,3,BC3,UP3,MSK3)
      STEP(16,4,0,BC4,UP4,MSK0) STEP(17,4,1,BC4,UP4,MSK1) STEP(18,4,2,BC4,UP4,MSK2) STEP(19,4,3,BC4,UP4,MSK3)
      STEP(20,5,0,BC5,UP5,MSK0) STEP(21,5,1,BC5,UP5,MSK1) STEP(22,5,2,BC5,UP5,MSK2) STEP(23,5,3,BC5,UP5,MSK3)
      STEP(24,6,0,BC6,UP6,MSK0) STEP(25,6,1,BC6,UP6,MSK1) STEP(26,6,2,BC6,UP6,MSK2) STEP(27,6,3,BC6,UP6,MSK3)
      STEP(28,7,0,BC7,UP7,MSK0) STEP(29,7,1,BC7,UP7,MSK1) STEP(30,7,2,BC7,UP7,MSK2) STEP(31,7,3,BC7,UP7,MSK3)

      // writeback fp32 L panel (uppers ~0 from uniform updates), exact unit diag
      ST(0) ST(1) ST(2) ST(3) ST(4) ST(5) ST(6) ST(7)
      if (lane < 32) Bm[r0][k0 + lane] = 1.0f;
      // bf16 operand panels for trailing update
      if (p < 3){
        if (h0 && lane >= 32) { WPROW(r0, ya0,ya1,ya2,ya3,ya4,ya5,ya6,ya7) }
        if (h1)               { WPROW(r1, yb0,yb1,yb2,yb3,yb4,yb5,yb6,yb7) }
      }
    }
    __syncthreads();
    if (p < 3){
      const int b0 = k0 + 32, n = 128 - b0, ntile = n >> 4;
      const int tiles = (ntile * (ntile + 1)) >> 1;
      const int nextra = ntile >> 1;  // super-diagonal band tiles
      const int ntot = tiles + nextra;
      const int lr = lane & 15, lk = lane >> 4;
      for (int idx = wv; idx < ntot; idx += 4){
        int i0, j0;
        if (idx >= tiles){
          int k = idx - tiles;
          i0 = b0 + (k << 5); j0 = i0 + 16;
        } else {
          int ti = 0;
          while ((ti + 1) * (ti + 2) / 2 <= idx) ++ti;
          int tj = idx - ti * (ti + 1) / 2;
          i0 = b0 + (ti << 4); j0 = b0 + (tj << 4);
        }
        int crow = i0 + (lk << 2), ccol = j0 + lr;
        f32x4 c;
        #pragma unroll
        for (int q = 0; q < 4; ++q) c[q] = Bm[crow + q][ccol];
        int pia = (i0 + lr) * 16 + (lk << 2);
        b16x8 af = *(const b16x8*)&Bm[pia >> 6][68 + (pia & 63)];
        int pib = (j0 + lr) * 16 + (lk << 2);
        b16x8 bfr = *(const b16x8*)&Bm[32 + (pib >> 6)][68 + (pib & 63)];
        c = __builtin_amdgcn_mfma_f32_16x16x32_bf16(af, bfr, c, 0, 0, 0);
        #pragma unroll
        for (int q = 0; q < 4; ++q) Bm[crow + q][ccol] = c[q];
      }
      __syncthreads();
    }
  }

  // zero strict-upper of diag 16x16 blocks (cheap insurance for 8a/8b reads)
  for (int e = tid; e < 2048; e += 256){
    int b = e >> 8, r = (e >> 4) & 15, c = e & 15;
    if (c > r) Bm[(b << 4) + r][(b << 4) + c] = 0.0f;
  }

  // phase 8a: invert 16x16 unit-lower diag blocks in place.
  if (wv < 2){
    const int g = lane >> 4, c8 = lane & 15;
    const int ib = ((wv << 2) + g) << 4;
    float Lr[16], x[16];
    #pragma unroll
    for (int r = 0; r < 16; ++r){
      Lr[r] = Bm[ib + r][ib + c8];
      x[r] = (r == c8) ? 1.0f : 0.0f;
    }
    #pragma unroll
    for (int k = 0; k < 15; ++k){
      float xk = x[k];
      #pragma unroll
      for (int r = k + 1; r < 16; ++r){
        float lrk = __shfl(Lr[r], (lane & 48) | k);
        x[r] -= lrk * xk;
      }
    }
    #pragma unroll
    for (int r = 1; r < 16; ++r)
      if (r > c8) Bm[ib + r][ib + c8] = x[r];
  }
  __syncthreads();

  // phase 8b: off-diagonal blocks of S = L~^{-1}, in place
  {
    const int xr = lane >> 2;
    const int xc = (lane & 3) << 2;
    for (int I = 1; I < 8; ++I){
      __syncthreads();
      for (int J = wv; J < I; J += 4){
        int slot = J >> 2;
        f32x4 tv = (f32x4){0.f, 0.f, 0.f, 0.f};
        for (int K = J; K < I; ++K){
          #pragma unroll
          for (int kk = 0; kk < 16; ++kk){
            float l = Bm[(I << 4) + xr][(K << 4) + kk];
            f32x4 srow = *(f32x4*)&Bm[(K << 4) + kk][(J << 4) + xc];
            tv += l * srow;
          }
        }
        *(f32x4*)&Tscr[wv][slot][xr][xc] = tv;
      }
      __syncthreads();
      for (int J = wv; J < I; J += 4){
        int slot = J >> 2;
        f32x4 x = *(f32x4*)&Tscr[wv][slot][xr][xc];
        for (int k = 0; k < xr; ++k){
          float sik = Bm[(I << 4) + xr][(I << 4) + k];
          x += sik * (*(f32x4*)&Tscr[wv][slot][k][xc]);
        }
        *(f32x4*)&Bm[(I << 4) + xr][(J << 4) + xc] = -x;
      }
    }
  }
  __syncthreads();

  // phase 9a/9b: row sweeps: trace partials, p = S v~
  if (tid < 128){
    int i = tid;
    float asq = 0.f, ap = 0.f;
    for (int j4 = 0; j4 <= (i >> 2); ++j4){
      f32x4 v = *(f32x4*)&Bm[i][j4 << 2];
      f32x4 uv = *(f32x4*)&utlv[j4 << 2];
      #pragma unroll
      for (int q = 0; q < 4; ++q){
        int j = (j4 << 2) + q;
        bool ok = (j <= i);
        float sv = ok ? v[q] : 0.f;
        asq += sv * sv;
        ap  += sv * (ok ? uv[q] : 0.f);
      }
    }
    pvec[i] = ap;
    trv[i] = asq / dvec[i];
  }
  __syncthreads();
  if (tid < 128){
    utlv[tid] = pvec[tid] / dvec[tid];          // g = p / d
    epsv[tid] = epsv[tid] * rsqrtf(dvec[tid]);  // h = eps~ / sqrt(d)
  }
  __syncthreads();
  // phase 9c/9d: column sweeps: qmu~ = S^T g ; w~ = qmu~ + S^T h
  if (tid < 128){
    int j = tid;
    float aq = 0.f, aw = 0.f;
    for (int i = j; i < 128; ++i){
      float sij = Bm[i][j];
      aq += sij * utlv[i];
      aw += sij * epsv[i];
    }
    qmuv[j] = aq;
    wtv[j] = aq + aw;
  }
  __syncthreads();
  // phase 9e: reductions + kl; 9f: write w
  float ra = 0.f, rb = 0.f, rc = 0.f;
  if (tid < 128){
    ra = trv[tid];
    float q = qmuv[tid];
    rb = q * q;
    rc = logf(dvec[tid]);
  }
  #pragma unroll
  for (int off = 32; off > 0; off >>= 1){
    ra += __shfl_xor(ra, off);
    rb += __shfl_xor(rb, off);
    rc += __shfl_xor(rc, off);
  }
  if (lane == 0){
    red[wv * 4 + 0] = ra; red[wv * 4 + 1] = rb; red[wv * 4 + 2] = rc;
  }
  __syncthreads();
  if (tid == 0){
    float tr = red[0] + red[4] + red[8]  + red[12];
    float q2 = red[1] + red[5] + red[9]  + red[13];
    float ld = red[2] + red[6] + red[10] + red[14];
    klso[(s << 7) + o] = 0.5f * (tr + q2 - 128.0f + ld);
  }
  if (tid < 128)
    wout[(((size_t)(s << 7) + o) << 7) + tid] = wtv[127 - tid];
}

// ---------------- K3: F_out / U_out GEMMs ----------------
__global__ __launch_bounds__(256, 2) void k3_outs(
    const float* __restrict__ F, const float* __restrict__ U,
    const float* __restrict__ wbuf, float* __restrict__ out)
{
  __shared__ __align__(16) ushort Ab[128][136];
  __shared__ __align__(16) ushort Wb[128][136];
  const int tid = threadIdx.x;
  const int lane = tid & 63, wv = tid >> 6;
  const int bid = blockIdx.x;
  const float* src;
  float* dst;
  int s;
  if (bid < 512){
    s = bid >> 5;
    int t = bid & 31;
    size_t off = (((size_t)s * 4096) + (size_t)t * 128) * 128;
    src = F + off;
    dst = out + off;
  } else {
    s = bid - 512;
    src = U + ((size_t)s << 14);
    dst = out + (size_t)8388608 + ((size_t)s << 14);
  }
  for (int e = tid * 4; e < 16384; e += 1024){
    f32x4 v = *(const f32x4*)&src[e];
    uint2 pv; pv.x = pk2(fmaxf(v[0],0.f), fmaxf(v[1],0.f));
    pv.y = pk2(fmaxf(v[2],0.f), fmaxf(v[3],0.f));
    *(uint2*)&Ab[e >> 7][e & 127] = pv;
  }
  const float* wsrc = wbuf + ((size_t)s << 14);
  for (int e = tid * 4; e < 16384; e += 1024){
    f32x4 v = *(const f32x4*)&wsrc[e];
    uint2 pv; pv.x = pk2(v[0], v[1]); pv.y = pk2(v[2], v[3]);
    *(uint2*)&Wb[e >> 7][e & 127] = pv;
  }
  __syncthreads();
  f32x4 acc[2][8];
  mfma128(Ab, Wb, acc, wv, lane);
  const int lr = lane & 15, lk = lane >> 4;
  #pragma unroll
  for (int ti = 0; ti < 2; ++ti){
    #pragma unroll
    for (int tj = 0; tj < 8; ++tj){
      int c = tj * 16 + lr;
      #pragma unroll
      for (int q = 0; q < 4; ++q){
        int r = (wv * 2 + ti) * 16 + lk * 4 + q;
        dst[(size_t)r * 128 + c] = acc[ti][tj][q];
      }
    }
  }
}

// ---------------- K4: kl reduction ----------------
__global__ void k4_klred(const float* __restrict__ klso, float* __restrict__ klout){
  __shared__ float sums[16][17];
  const int t = threadIdx.x;
  int s = t >> 4, ch = t & 15;
  float a = 0.f;
  for (int q = 0; q < 8; ++q) a += klso[(s << 7) + ch * 8 + q];
  sums[s][ch] = a;
  __syncthreads();
  if (t < 16){
    float r = 0.f;
    for (int c = 0; c < 16; ++c) r += sums[t][c];
    klout[t] = r;
  }
}

extern "C" void kernel_launch(void* const* d_in, const int* in_sizes, int n_in,
                              void* d_out, int out_size, void* d_ws, size_t ws_size,
                              hipStream_t stream) {
  const float* F   = (const float*)d_in[0];
  const float* U   = (const float*)d_in[1];
  const float* mu  = (const float*)d_in[2];
  const float* lp  = (const float*)d_in[3];
  const float* eps = (const float*)d_in[4];
  float* out = (float*)d_out;
  char* ws = (char*)d_ws;
  ushort* phiUT = (ushort*)(ws + PHIUT_OFF);
  float* sqlp = (float*)(ws + SQLP_OFF);
  float* smu  = (float*)(ws + SMU_OFF);
  float* wbuf = (float*)(ws + WBUF_OFF);
  float* klso = (float*)(ws + KLSO_OFF);

  k0_prep<<<dim3(80), dim3(256), 0, stream>>>(U, mu, lp, phiUT, sqlp, smu);
  k2_factor<<<dim3(2048), dim3(256), 0, stream>>>(phiUT, sqlp, smu, eps, wbuf, klso);
  k3_outs<<<dim3(528), dim3(256), 0, stream>>>(F, U, wbuf, out);
  k4_klred<<<dim3(1), dim3(256), 0, stream>>>(klso, out + 8650752);
}

// Round 6
// 450.355 us; speedup vs baseline: 2.9358x; 2.9358x over previous
//
#include <hip/hip_runtime.h>

typedef unsigned int uint;
typedef unsigned short ushort;
typedef __attribute__((ext_vector_type(8))) short b16x8;
typedef __attribute__((ext_vector_type(4))) float f32x4;

// ws byte offsets
#define PHIUT_OFF 0u
#define SQLP_OFF  524288u
#define SMU_OFF   (524288u + 65536u)
#define WBUF_OFF  (524288u + 131072u)
#define KLSO_OFF  (524288u + 131072u + 1048576u)

__device__ __forceinline__ ushort f2bf(float x){
  union { float f; uint u; } v; v.f = x;
  uint r = v.u + 0x7fffu + ((v.u >> 16) & 1u);
  return (ushort)(r >> 16);
}
__device__ __forceinline__ float bflo(uint u){ union { uint uu; float f; } v; v.uu = u << 16; return v.f; }
__device__ __forceinline__ float bfhi(uint u){ union { uint uu; float f; } v; v.uu = u & 0xffff0000u; return v.f; }
__device__ __forceinline__ uint pk2(float a, float b){ return (uint)f2bf(a) | ((uint)f2bf(b) << 16); }
// wave-uniform broadcast: result lives in SGPR, not VGPR
__device__ __forceinline__ float rdl(float x, int l){
  union { float f; int i; } u; u.f = x;
  u.i = __builtin_amdgcn_readlane(u.i, l);
  return u.f;
}

// C = A_rows · B_rows^T (NT), 128x128x128, bf16 MFMA 16x16x32.
__device__ __forceinline__ void mfma128(const ushort (*A)[136], const ushort (*B)[136],
                                        f32x4 acc[2][8], int wv, int lane){
  const int lr = lane & 15, lk = lane >> 4;
  #pragma unroll
  for (int ti = 0; ti < 2; ++ti)
    #pragma unroll
    for (int tj = 0; tj < 8; ++tj)
      acc[ti][tj] = (f32x4){0.f, 0.f, 0.f, 0.f};
  #pragma unroll
  for (int kk = 0; kk < 4; ++kk){
    const int kof = kk * 32 + lk * 8;
    b16x8 a0 = *(const b16x8*)&A[(wv * 2 + 0) * 16 + lr][kof];
    b16x8 a1 = *(const b16x8*)&A[(wv * 2 + 1) * 16 + lr][kof];
    #pragma unroll
    for (int tj = 0; tj < 8; ++tj){
      b16x8 bf = *(const b16x8*)&B[tj * 16 + lr][kof];
      acc[0][tj] = __builtin_amdgcn_mfma_f32_16x16x32_bf16(a0, bf, acc[0][tj], 0, 0, 0);
      acc[1][tj] = __builtin_amdgcn_mfma_f32_16x16x32_bf16(a1, bf, acc[1][tj], 0, 0, 0);
    }
  }
}

// ---------------- K0: prep (phiU^T bf16, exp(lp/2), exp(lp/2)*mu) ----------------
__global__ void k0_prep(const float* __restrict__ U, const float* __restrict__ mu,
                        const float* __restrict__ lp, ushort* __restrict__ phiUT,
                        float* __restrict__ sqlp, float* __restrict__ smu)
{
  __shared__ __align__(16) ushort T0[128][132];
  const int tid = threadIdx.x;
  const int bid = blockIdx.x;
  if (bid < 16){
    const float* Us = U + ((size_t)bid << 14);
    for (int e = tid * 4; e < 16384; e += 1024){
      f32x4 v = *(const f32x4*)&Us[e];
      int m = e >> 7, d = e & 127;
      uint2 pv; pv.x = pk2(fmaxf(v[0],0.f), fmaxf(v[1],0.f));
      pv.y = pk2(fmaxf(v[2],0.f), fmaxf(v[3],0.f));
      *(uint2*)&T0[m][d] = pv;
    }
    __syncthreads();
    ushort* op = phiUT + ((size_t)bid << 14);
    for (int e = tid; e < 16384; e += 256){
      int d = e >> 7, m2 = e & 127;
      op[e] = T0[m2][d];
    }
  } else {
    int idx = ((bid - 16) << 8) + tid;
    float l = lp[idx], m = mu[idx];
    float ex = expf(0.5f * l);
    sqlp[idx] = ex;
    smu[idx]  = ex * m;
  }
}

// ===== static in-register 128x32 panel LDL; broadcasts via readlane (SGPR) =====
// Non-pivot 4-col group J: read 4 lanes as scalars, fuse immediately.
#define UPJ(J, T) { \
  float s0_=rdl(ya##J[0],(T)), s1_=rdl(ya##J[1],(T)), s2_=rdl(ya##J[2],(T)), s3_=rdl(ya##J[3],(T)); \
  ya##J[0] -= m0_*s0_; ya##J[1] -= m0_*s1_; ya##J[2] -= m0_*s2_; ya##J[3] -= m0_*s3_; \
  yb##J[0] -= m1_*s0_; yb##J[1] -= m1_*s1_; yb##J[2] -= m1_*s2_; yb##J[3] -= m1_*s3_; }

// Pivot 4-col group (J == T4), variant by TQ: comps < TQ untouched (L values),
// comp TQ := multiplier, comps > TQ get the rank-1 update.
#define UPP0(P,T) { float s1_=rdl(ya##P[1],(T)), s2_=rdl(ya##P[2],(T)), s3_=rdl(ya##P[3],(T)); \
  ya##P[1]-=m0_*s1_; ya##P[2]-=m0_*s2_; ya##P[3]-=m0_*s3_; ya##P[0]=m0_; \
  yb##P[1]-=m1_*s1_; yb##P[2]-=m1_*s2_; yb##P[3]-=m1_*s3_; yb##P[0]=m1_; }
#define UPP1(P,T) { float s2_=rdl(ya##P[2],(T)), s3_=rdl(ya##P[3],(T)); \
  ya##P[2]-=m0_*s2_; ya##P[3]-=m0_*s3_; ya##P[1]=m0_; \
  yb##P[2]-=m1_*s2_; yb##P[3]-=m1_*s3_; yb##P[1]=m1_; }
#define UPP2(P,T) { float s3_=rdl(ya##P[3],(T)); \
  ya##P[3]-=m0_*s3_; ya##P[2]=m0_; \
  yb##P[3]-=m1_*s3_; yb##P[2]=m1_; }
#define UPP3(P,T) { ya##P[3]=m0_; yb##P[3]=m1_; }

#define TAIL7(T)
#define TAIL6(T) UPJ(7,T)
#define TAIL5(T) UPJ(6,T) TAIL6(T)
#define TAIL4(T) UPJ(5,T) TAIL5(T)
#define TAIL3(T) UPJ(4,T) TAIL4(T)
#define TAIL2(T) UPJ(3,T) TAIL3(T)
#define TAIL1(T) UPJ(2,T) TAIL2(T)
#define TAIL0(T) UPJ(1,T) TAIL1(T)

#define STEP(T, T4, TQ) { \
  float d_ = rdl(ya##T4[TQ], (T)); \
  if (lane == 0) dvec[k0 + (T)] = d_; \
  float rk_ = 1.0f / d_; \
  float m0_ = ya##T4[TQ] * rk_; \
  float m1_ = yb##T4[TQ] * rk_; \
  UPP##TQ(T4, T) \
  TAIL##T4(T) }

#define LD(J) ya##J = h0 ? *(f32x4*)&Bm[r0][k0 + 4*(J)] : z4; \
              yb##J = h1 ? *(f32x4*)&Bm[r1][k0 + 4*(J)] : z4;
#define ST(J) if (h0) *(f32x4*)&Bm[r0][k0 + 4*(J)] = ya##J; \
              if (h1) *(f32x4*)&Bm[r1][k0 + 4*(J)] = yb##J;

// bf16 operand writeback (PA = -L*D rows 0..31, PB = L rows 32..63, cols 68..131)
#define WPQ(ROW, Y0, Y1, Q) { \
  f32x4 d0_ = *(const f32x4*)&dvec[k0 + (Q)*8]; \
  f32x4 d1_ = *(const f32x4*)&dvec[k0 + (Q)*8 + 4]; \
  f32x4 a0_ = (f32x4){0.f,0.f,0.f,0.f} - Y0 * d0_; \
  f32x4 a1_ = (f32x4){0.f,0.f,0.f,0.f} - Y1 * d1_; \
  uint4 ua_, ub_; \
  ua_.x = pk2(a0_[0],a0_[1]); ua_.y = pk2(a0_[2],a0_[3]); \
  ua_.z = pk2(a1_[0],a1_[1]); ua_.w = pk2(a1_[2],a1_[3]); \
  ub_.x = pk2(Y0[0],Y0[1]);   ub_.y = pk2(Y0[2],Y0[3]); \
  ub_.z = pk2(Y1[0],Y1[1]);   ub_.w = pk2(Y1[2],Y1[3]); \
  int fidx_ = (ROW)*16 + (Q)*4; \
  *(uint4*)&Bm[fidx_ >> 6][68 + (fidx_ & 63)] = ua_; \
  *(uint4*)&Bm[32 + (fidx_ >> 6)][68 + (fidx_ & 63)] = ub_; }
#define WPROW(ROW, V0,V1,V2,V3,V4,V5,V6,V7) \
  WPQ(ROW, V0, V1, 0) WPQ(ROW, V2, V3, 1) WPQ(ROW, V4, V5, 2) WPQ(ROW, V6, V7, 3)

// ---------------- K2: per-(s,o) factorization ----------------
// Reversed space: B = J A J = Wt·Wt^T + I. LDL: B = L~ D L~^T ; S = L~^{-1}.
// logdet_prec = Σ log d_k ; tr(q_cov) = Σ_i ||S row i||²/d_i
// p = S v~ ; qmu~ = S^T (p/d) ; w~ = qmu~ + S^T (eps~/√d) ; w[d] = w~[127-d]
__global__ __launch_bounds__(256, 2) void k2_factor(
    const ushort* __restrict__ phiUT, const float* __restrict__ sqlp,
    const float* __restrict__ smu, const float* __restrict__ eps,
    float* __restrict__ wout, float* __restrict__ klso)
{
  __shared__ __align__(16) float Bm[128][132];
  __shared__ __align__(16) float Tscr[4][2][16][16];
  __shared__ __align__(16) float svec[128];
  __shared__ __align__(16) float smuv[128];
  __shared__ __align__(16) float epsv[128];
  __shared__ __align__(16) float utlv[128];
  __shared__ __align__(16) float dvec[128];
  __shared__ __align__(16) float pvec[128];
  __shared__ __align__(16) float qmuv[128];
  __shared__ __align__(16) float wtv[128];
  float* trv = smuv;   // smuv dead after phase 3
  float* red = svec;   // svec dead after phase 2
  ushort (*Wt)[136] = (ushort (*)[136])&Bm[0][0];

  const int tid  = threadIdx.x;
  const int lane = tid & 63;
  const int wv   = tid >> 6;
  const int s    = blockIdx.x >> 7;
  const int o    = blockIdx.x & 127;

  // phase 1: vectors
  if (tid < 128){
    svec[tid] = sqlp[(o << 7) + tid];
    epsv[tid] = eps[(((size_t)s * 128 + o) << 7) + 127 - tid];
  } else {
    int t2 = tid - 128;
    smuv[t2] = smu[(o << 7) + t2];
  }
  __syncthreads();

  // phase 2: Wt fill (reversed rows, scaled, bf16)
  for (int e = tid * 8; e < 16384; e += 2048){
    int dp = e >> 7, m = e & 127;
    const ushort* srcp = phiUT + (((size_t)s) << 14) + ((size_t)(127 - dp) << 7) + m;
    uint4 raw = *(const uint4*)srcp;
    f32x4 c0 = *(f32x4*)&svec[m];
    f32x4 c1 = *(f32x4*)&svec[m + 4];
    uint4 ov;
    ov.x = pk2(bflo(raw.x)*c0[0], bfhi(raw.x)*c0[1]);
    ov.y = pk2(bflo(raw.y)*c0[2], bfhi(raw.y)*c0[3]);
    ov.z = pk2(bflo(raw.z)*c1[0], bfhi(raw.z)*c1[1]);
    ov.w = pk2(bflo(raw.w)*c1[2], bfhi(raw.w)*c1[3]);
    *(uint4*)&Wt[dp][m] = ov;
  }
  __syncthreads();

  // phase 3: v~ = Wt · (sqrtLp ⊙ mu)
  if (tid < 128){
    float acc3 = 0.f;
    for (int m = 0; m < 128; m += 8){
      uint4 raw = *(uint4*)&Wt[tid][m];
      f32x4 u0 = *(f32x4*)&smuv[m];
      f32x4 u1 = *(f32x4*)&smuv[m + 4];
      acc3 += bflo(raw.x) * u0[0] + bfhi(raw.x) * u0[1]
            + bflo(raw.y) * u0[2] + bfhi(raw.y) * u0[3]
            + bflo(raw.z) * u1[0] + bfhi(raw.z) * u1[1]
            + bflo(raw.w) * u1[2] + bfhi(raw.w) * u1[3];
    }
    utlv[tid] = acc3;
  }
  __syncthreads();

  // phase 4: MFMA Gram
  f32x4 acc[2][8];
  mfma128(Wt, Wt, acc, wv, lane);
  __syncthreads();  // Wt reads complete before overwrite

  // phase 5: Bm = Gram + I (full matrix)
  {
    const int lr = lane & 15, lk = lane >> 4;
    #pragma unroll
    for (int ti = 0; ti < 2; ++ti){
      #pragma unroll
      for (int tj = 0; tj < 8; ++tj){
        int c = tj * 16 + lr;
        #pragma unroll
        for (int q = 0; q < 4; ++q){
          int r = (wv * 2 + ti) * 16 + lk * 4 + q;
          float v = acc[ti][tj][q];
          if (r == c) v += 1.0f;
          Bm[r][c] = v;
        }
      }
    }
  }
  __syncthreads();

  // phase 6: blocked LDL, panel width 32. wave0 factors the 128x32 panel in
  // static registers (readlane broadcasts -> SGPR, no LDS ping-pong); all
  // waves apply MFMA bf16 trailing update, incl. super-diagonal band tiles
  // at every future panel boundary.
  for (int p = 0; p < 4; ++p){
    const int k0 = p << 5;
    const int nrows = 128 - k0;
    if (wv == 0){
      const int r0 = k0 + lane, r1 = k0 + 64 + lane;
      const bool h0 = lane < nrows;
      const bool h1 = (64 + lane) < nrows;
      const f32x4 z4 = (f32x4){0.f,0.f,0.f,0.f};
      f32x4 ya0,ya1,ya2,ya3,ya4,ya5,ya6,ya7;
      f32x4 yb0,yb1,yb2,yb3,yb4,yb5,yb6,yb7;
      LD(0) LD(1) LD(2) LD(3) LD(4) LD(5) LD(6) LD(7)

      STEP( 0,0,0) STEP( 1,0,1) STEP( 2,0,2) STEP( 3,0,3)
      STEP( 4,1,0) STEP( 5,1,1) STEP( 6,1,2) STEP( 7,1,3)
      STEP( 8,2,0) STEP( 9,2,1) STEP(10,2,2) STEP(11,2,3)
      STEP(12,3,0) STEP(13,3,1) STEP(14,3,2) STEP(15,3,3)
      STEP(16,4,0) STEP(17,4,1) STEP(18,4,2) STEP(19,4,3)
      STEP(20,5,0) STEP(21,5,1) STEP(22,5,2) STEP(23,5,3)
      STEP(24,6,0) STEP(25,6,1) STEP(26,6,2) STEP(27,6,3)
      STEP(28,7,0) STEP(29,7,1) STEP(30,7,2) STEP(31,7,3)

      // writeback fp32 L panel (pivot-block strict upper is exact zeros)
      ST(0) ST(1) ST(2) ST(3) ST(4) ST(5) ST(6) ST(7)
      if (lane < 32) Bm[r0][k0 + lane] = 1.0f;
      // bf16 operand panels for trailing update
      if (p < 3){
        if (h0 && lane >= 32) { WPROW(r0, ya0,ya1,ya2,ya3,ya4,ya5,ya6,ya7) }
        if (h1)               { WPROW(r1, yb0,yb1,yb2,yb3,yb4,yb5,yb6,yb7) }
      }
    }
    __syncthreads();
    if (p < 3){
      const int b0 = k0 + 32, n = 128 - b0, ntile = n >> 4;
      const int tiles = (ntile * (ntile + 1)) >> 1;
      const int nextra = ntile >> 1;  // super-diagonal band tiles
      const int ntot = tiles + nextra;
      const int lr = lane & 15, lk = lane >> 4;
      for (int idx = wv; idx < ntot; idx += 4){
        int i0, j0;
        if (idx >= tiles){
          int k = idx - tiles;
          i0 = b0 + (k << 5); j0 = i0 + 16;
        } else {
          int ti = 0;
          while ((ti + 1) * (ti + 2) / 2 <= idx) ++ti;
          int tj = idx - ti * (ti + 1) / 2;
          i0 = b0 + (ti << 4); j0 = b0 + (tj << 4);
        }
        int crow = i0 + (lk << 2), ccol = j0 + lr;
        f32x4 c;
        #pragma unroll
        for (int q = 0; q < 4; ++q) c[q] = Bm[crow + q][ccol];
        int pia = (i0 + lr) * 16 + (lk << 2);
        b16x8 af = *(const b16x8*)&Bm[pia >> 6][68 + (pia & 63)];
        int pib = (j0 + lr) * 16 + (lk << 2);
        b16x8 bfr = *(const b16x8*)&Bm[32 + (pib >> 6)][68 + (pib & 63)];
        c = __builtin_amdgcn_mfma_f32_16x16x32_bf16(af, bfr, c, 0, 0, 0);
        #pragma unroll
        for (int q = 0; q < 4; ++q) Bm[crow + q][ccol] = c[q];
      }
      __syncthreads();
    }
  }

  // zero strict-upper of diag 16x16 blocks (cheap insurance for 8a/8b reads)
  for (int e = tid; e < 2048; e += 256){
    int b = e >> 8, r = (e >> 4) & 15, c = e & 15;
    if (c > r) Bm[(b << 4) + r][(b << 4) + c] = 0.0f;
  }

  // phase 8a: invert 16x16 unit-lower diag blocks in place.
  if (wv < 2){
    const int g = lane >> 4, c8 = lane & 15;
    const int ib = ((wv << 2) + g) << 4;
    float Lr[16], x[16];
    #pragma unroll
    for (int r = 0; r < 16; ++r){
      Lr[r] = Bm[ib + r][ib + c8];
      x[r] = (r == c8) ? 1.0f : 0.0f;
    }
    #pragma unroll
    for (int k = 0; k < 15; ++k){
      float xk = x[k];
      #pragma unroll
      for (int r = k + 1; r < 16; ++r){
        float lrk = __shfl(Lr[r], (lane & 48) | k);
        x[r] -= lrk * xk;
      }
    }
    #pragma unroll
    for (int r = 1; r < 16; ++r)
      if (r > c8) Bm[ib + r][ib + c8] = x[r];
  }
  __syncthreads();

  // phase 8b: off-diagonal blocks of S = L~^{-1}, in place
  {
    const int xr = lane >> 2;
    const int xc = (lane & 3) << 2;
    for (int I = 1; I < 8; ++I){
      __syncthreads();
      for (int J = wv; J < I; J += 4){
        int slot = J >> 2;
        f32x4 tv = (f32x4){0.f, 0.f, 0.f, 0.f};
        for (int K = J; K < I; ++K){
          #pragma unroll
          for (int kk = 0; kk < 16; ++kk){
            float l = Bm[(I << 4) + xr][(K << 4) + kk];
            f32x4 srow = *(f32x4*)&Bm[(K << 4) + kk][(J << 4) + xc];
            tv += l * srow;
          }
        }
        *(f32x4*)&Tscr[wv][slot][xr][xc] = tv;
      }
      __syncthreads();
      for (int J = wv; J < I; J += 4){
        int slot = J >> 2;
        f32x4 x = *(f32x4*)&Tscr[wv][slot][xr][xc];
        for (int k = 0; k < xr; ++k){
          float sik = Bm[(I << 4) + xr][(I << 4) + k];
          x += sik * (*(f32x4*)&Tscr[wv][slot][k][xc]);
        }
        *(f32x4*)&Bm[(I << 4) + xr][(J << 4) + xc] = -x;
      }
    }
  }
  __syncthreads();

  // phase 9a/9b: row sweeps: trace partials, p = S v~
  if (tid < 128){
    int i = tid;
    float asq = 0.f, ap = 0.f;
    for (int j4 = 0; j4 <= (i >> 2); ++j4){
      f32x4 v = *(f32x4*)&Bm[i][j4 << 2];
      f32x4 uv = *(f32x4*)&utlv[j4 << 2];
      #pragma unroll
      for (int q = 0; q < 4; ++q){
        int j = (j4 << 2) + q;
        bool ok = (j <= i);
        float sv = ok ? v[q] : 0.f;
        asq += sv * sv;
        ap  += sv * (ok ? uv[q] : 0.f);
      }
    }
    pvec[i] = ap;
    trv[i] = asq / dvec[i];
  }
  __syncthreads();
  if (tid < 128){
    utlv[tid] = pvec[tid] / dvec[tid];          // g = p / d
    epsv[tid] = epsv[tid] * rsqrtf(dvec[tid]);  // h = eps~ / sqrt(d)
  }
  __syncthreads();
  // phase 9c/9d: column sweeps: qmu~ = S^T g ; w~ = qmu~ + S^T h
  if (tid < 128){
    int j = tid;
    float aq = 0.f, aw = 0.f;
    for (int i = j; i < 128; ++i){
      float sij = Bm[i][j];
      aq += sij * utlv[i];
      aw += sij * epsv[i];
    }
    qmuv[j] = aq;
    wtv[j] = aq + aw;
  }
  __syncthreads();
  // phase 9e: reductions + kl; 9f: write w
  float ra = 0.f, rb = 0.f, rc = 0.f;
  if (tid < 128){
    ra = trv[tid];
    float q = qmuv[tid];
    rb = q * q;
    rc = logf(dvec[tid]);
  }
  #pragma unroll
  for (int off = 32; off > 0; off >>= 1){
    ra += __shfl_xor(ra, off);
    rb += __shfl_xor(rb, off);
    rc += __shfl_xor(rc, off);
  }
  if (lane == 0){
    red[wv * 4 + 0] = ra; red[wv * 4 + 1] = rb; red[wv * 4 + 2] = rc;
  }
  __syncthreads();
  if (tid == 0){
    float tr = red[0] + red[4] + red[8]  + red[12];
    float q2 = red[1] + red[5] + red[9]  + red[13];
    float ld = red[2] + red[6] + red[10] + red[14];
    klso[(s << 7) + o] = 0.5f * (tr + q2 - 128.0f + ld);
  }
  if (tid < 128)
    wout[(((size_t)(s << 7) + o) << 7) + tid] = wtv[127 - tid];
}

// ---------------- K3: F_out / U_out GEMMs ----------------
__global__ __launch_bounds__(256, 2) void k3_outs(
    const float* __restrict__ F, const float* __restrict__ U,
    const float* __restrict__ wbuf, float* __restrict__ out)
{
  __shared__ __align__(16) ushort Ab[128][136];
  __shared__ __align__(16) ushort Wb[128][136];
  const int tid = threadIdx.x;
  const int lane = tid & 63, wv = tid >> 6;
  const int bid = blockIdx.x;
  const float* src;
  float* dst;
  int s;
  if (bid < 512){
    s = bid >> 5;
    int t = bid & 31;
    size_t off = (((size_t)s * 4096) + (size_t)t * 128) * 128;
    src = F + off;
    dst = out + off;
  } else {
    s = bid - 512;
    src = U + ((size_t)s << 14);
    dst = out + (size_t)8388608 + ((size_t)s << 14);
  }
  for (int e = tid * 4; e < 16384; e += 1024){
    f32x4 v = *(const f32x4*)&src[e];
    uint2 pv; pv.x = pk2(fmaxf(v[0],0.f), fmaxf(v[1],0.f));
    pv.y = pk2(fmaxf(v[2],0.f), fmaxf(v[3],0.f));
    *(uint2*)&Ab[e >> 7][e & 127] = pv;
  }
  const float* wsrc = wbuf + ((size_t)s << 14);
  for (int e = tid * 4; e < 16384; e += 1024){
    f32x4 v = *(const f32x4*)&wsrc[e];
    uint2 pv; pv.x = pk2(v[0], v[1]); pv.y = pk2(v[2], v[3]);
    *(uint2*)&Wb[e >> 7][e & 127] = pv;
  }
  __syncthreads();
  f32x4 acc[2][8];
  mfma128(Ab, Wb, acc, wv, lane);
  const int lr = lane & 15, lk = lane >> 4;
  #pragma unroll
  for (int ti = 0; ti < 2; ++ti){
    #pragma unroll
    for (int tj = 0; tj < 8; ++tj){
      int c = tj * 16 + lr;
      #pragma unroll
      for (int q = 0; q < 4; ++q){
        int r = (wv * 2 + ti) * 16 + lk * 4 + q;
        dst[(size_t)r * 128 + c] = acc[ti][tj][q];
      }
    }
  }
}

// ---------------- K4: kl reduction ----------------
__global__ void k4_klred(const float* __restrict__ klso, float* __restrict__ klout){
  __shared__ float sums[16][17];
  const int t = threadIdx.x;
  int s = t >> 4, ch = t & 15;
  float a = 0.f;
  for (int q = 0; q < 8; ++q) a += klso[(s << 7) + ch * 8 + q];
  sums[s][ch] = a;
  __syncthreads();
  if (t < 16){
    float r = 0.f;
    for (int c = 0; c < 16; ++c) r += sums[t][c];
    klout[t] = r;
  }
}

extern "C" void kernel_launch(void* const* d_in, const int* in_sizes, int n_in,
                              void* d_out, int out_size, void* d_ws, size_t ws_size,
                              hipStream_t stream) {
  const float* F   = (const float*)d_in[0];
  const float* U   = (const float*)d_in[1];
  const float* mu  = (const float*)d_in[2];
  const float* lp  = (const float*)d_in[3];
  const float* eps = (const float*)d_in[4];
  float* out = (float*)d_out;
  char* ws = (char*)d_ws;
  ushort* phiUT = (ushort*)(ws + PHIUT_OFF);
  float* sqlp = (float*)(ws + SQLP_OFF);
  float* smu  = (float*)(ws + SMU_OFF);
  float* wbuf = (float*)(ws + WBUF_OFF);
  float* klso = (float*)(ws + KLSO_OFF);

  k0_prep<<<dim3(80), dim3(256), 0, stream>>>(U, mu, lp, phiUT, sqlp, smu);
  k2_factor<<<dim3(2048), dim3(256), 0, stream>>>(phiUT, sqlp, smu, eps, wbuf, klso);
  k3_outs<<<dim3(528), dim3(256), 0, stream>>>(F, U, wbuf, out);
  k4_klred<<<dim3(1), dim3(256), 0, stream>>>(klso, out + 8650752);
}

// Round 7
// 412.676 us; speedup vs baseline: 3.2039x; 1.0913x over previous
//
#include <hip/hip_runtime.h>

typedef unsigned int uint;
typedef unsigned short ushort;
typedef __attribute__((ext_vector_type(8))) short b16x8;
typedef __attribute__((ext_vector_type(4))) float f32x4;

// ws byte offsets
#define PHIUT_OFF 0u
#define SQLP_OFF  524288u
#define SMU_OFF   (524288u + 65536u)
#define WBUF_OFF  (524288u + 131072u)
#define KLSO_OFF  (524288u + 131072u + 1048576u)

__device__ __forceinline__ ushort f2bf(float x){
  union { float f; uint u; } v; v.f = x;
  uint r = v.u + 0x7fffu + ((v.u >> 16) & 1u);
  return (ushort)(r >> 16);
}
__device__ __forceinline__ float bflo(uint u){ union { uint uu; float f; } v; v.uu = u << 16; return v.f; }
__device__ __forceinline__ float bfhi(uint u){ union { uint uu; float f; } v; v.uu = u & 0xffff0000u; return v.f; }
__device__ __forceinline__ uint pk2(float a, float b){ return (uint)f2bf(a) | ((uint)f2bf(b) << 16); }
// wave-uniform broadcast: result lives in SGPR, not VGPR
__device__ __forceinline__ float rdl(float x, int l){
  union { float f; int i; } u; u.f = x;
  u.i = __builtin_amdgcn_readlane(u.i, l);
  return u.f;
}

// C = A_rows · B_rows^T (NT), 128x128x128, bf16 MFMA 16x16x32.
__device__ __forceinline__ void mfma128(const ushort (*A)[136], const ushort (*B)[136],
                                        f32x4 acc[2][8], int wv, int lane){
  const int lr = lane & 15, lk = lane >> 4;
  #pragma unroll
  for (int ti = 0; ti < 2; ++ti)
    #pragma unroll
    for (int tj = 0; tj < 8; ++tj)
      acc[ti][tj] = (f32x4){0.f, 0.f, 0.f, 0.f};
  #pragma unroll
  for (int kk = 0; kk < 4; ++kk){
    const int kof = kk * 32 + lk * 8;
    b16x8 a0 = *(const b16x8*)&A[(wv * 2 + 0) * 16 + lr][kof];
    b16x8 a1 = *(const b16x8*)&A[(wv * 2 + 1) * 16 + lr][kof];
    #pragma unroll
    for (int tj = 0; tj < 8; ++tj){
      b16x8 bf = *(const b16x8*)&B[tj * 16 + lr][kof];
      acc[0][tj] = __builtin_amdgcn_mfma_f32_16x16x32_bf16(a0, bf, acc[0][tj], 0, 0, 0);
      acc[1][tj] = __builtin_amdgcn_mfma_f32_16x16x32_bf16(a1, bf, acc[1][tj], 0, 0, 0);
    }
  }
}

// ---------------- K0: prep (phiU^T bf16, exp(lp/2), exp(lp/2)*mu) ----------------
__global__ void k0_prep(const float* __restrict__ U, const float* __restrict__ mu,
                        const float* __restrict__ lp, ushort* __restrict__ phiUT,
                        float* __restrict__ sqlp, float* __restrict__ smu)
{
  __shared__ __align__(16) ushort T0[128][132];
  const int tid = threadIdx.x;
  const int bid = blockIdx.x;
  if (bid < 16){
    const float* Us = U + ((size_t)bid << 14);
    for (int e = tid * 4; e < 16384; e += 1024){
      f32x4 v = *(const f32x4*)&Us[e];
      int m = e >> 7, d = e & 127;
      uint2 pv; pv.x = pk2(fmaxf(v[0],0.f), fmaxf(v[1],0.f));
      pv.y = pk2(fmaxf(v[2],0.f), fmaxf(v[3],0.f));
      *(uint2*)&T0[m][d] = pv;
    }
    __syncthreads();
    ushort* op = phiUT + ((size_t)bid << 14);
    for (int e = tid; e < 16384; e += 256){
      int d = e >> 7, m2 = e & 127;
      op[e] = T0[m2][d];
    }
  } else {
    int idx = ((bid - 16) << 8) + tid;
    float l = lp[idx], m = mu[idx];
    float ex = expf(0.5f * l);
    sqlp[idx] = ex;
    smu[idx]  = ex * m;
  }
}

// ===== static in-register 128x32 panel LDL; broadcasts via readlane (SGPR) =====
#define UPJ(J, T) { \
  float s0_=rdl(ya##J[0],(T)), s1_=rdl(ya##J[1],(T)), s2_=rdl(ya##J[2],(T)), s3_=rdl(ya##J[3],(T)); \
  ya##J[0] -= m0_*s0_; ya##J[1] -= m0_*s1_; ya##J[2] -= m0_*s2_; ya##J[3] -= m0_*s3_; \
  yb##J[0] -= m1_*s0_; yb##J[1] -= m1_*s1_; yb##J[2] -= m1_*s2_; yb##J[3] -= m1_*s3_; }

#define UPP0(P,T) { float s1_=rdl(ya##P[1],(T)), s2_=rdl(ya##P[2],(T)), s3_=rdl(ya##P[3],(T)); \
  ya##P[1]-=m0_*s1_; ya##P[2]-=m0_*s2_; ya##P[3]-=m0_*s3_; ya##P[0]=m0_; \
  yb##P[1]-=m1_*s1_; yb##P[2]-=m1_*s2_; yb##P[3]-=m1_*s3_; yb##P[0]=m1_; }
#define UPP1(P,T) { float s2_=rdl(ya##P[2],(T)), s3_=rdl(ya##P[3],(T)); \
  ya##P[2]-=m0_*s2_; ya##P[3]-=m0_*s3_; ya##P[1]=m0_; \
  yb##P[2]-=m1_*s2_; yb##P[3]-=m1_*s3_; yb##P[1]=m1_; }
#define UPP2(P,T) { float s3_=rdl(ya##P[3],(T)); \
  ya##P[3]-=m0_*s3_; ya##P[2]=m0_; \
  yb##P[3]-=m1_*s3_; yb##P[2]=m1_; }
#define UPP3(P,T) { ya##P[3]=m0_; yb##P[3]=m1_; }

#define TAIL7(T)
#define TAIL6(T) UPJ(7,T)
#define TAIL5(T) UPJ(6,T) TAIL6(T)
#define TAIL4(T) UPJ(5,T) TAIL5(T)
#define TAIL3(T) UPJ(4,T) TAIL4(T)
#define TAIL2(T) UPJ(3,T) TAIL3(T)
#define TAIL1(T) UPJ(2,T) TAIL2(T)
#define TAIL0(T) UPJ(1,T) TAIL1(T)

#define STEP(T, T4, TQ) { \
  float d_ = rdl(ya##T4[TQ], (T)); \
  if (lane == 0) dvec[k0 + (T)] = d_; \
  float rk_ = 1.0f / d_; \
  float m0_ = ya##T4[TQ] * rk_; \
  float m1_ = yb##T4[TQ] * rk_; \
  UPP##TQ(T4, T) \
  TAIL##T4(T) }

#define LD(J) ya##J = h0 ? *(f32x4*)&Bm[r0][k0 + 4*(J)] : z4; \
              yb##J = h1 ? *(f32x4*)&Bm[r1][k0 + 4*(J)] : z4;
#define ST(J) if (h0) *(f32x4*)&Bm[r0][k0 + 4*(J)] = ya##J; \
              if (h1) *(f32x4*)&Bm[r1][k0 + 4*(J)] = yb##J;

// bf16 operand writeback (PA = -L*D rows 0..31, PB = L rows 32..63, cols 68..131)
#define WPQ(ROW, Y0, Y1, Q) { \
  f32x4 d0_ = *(const f32x4*)&dvec[k0 + (Q)*8]; \
  f32x4 d1_ = *(const f32x4*)&dvec[k0 + (Q)*8 + 4]; \
  f32x4 a0_ = (f32x4){0.f,0.f,0.f,0.f} - Y0 * d0_; \
  f32x4 a1_ = (f32x4){0.f,0.f,0.f,0.f} - Y1 * d1_; \
  uint4 ua_, ub_; \
  ua_.x = pk2(a0_[0],a0_[1]); ua_.y = pk2(a0_[2],a0_[3]); \
  ua_.z = pk2(a1_[0],a1_[1]); ua_.w = pk2(a1_[2],a1_[3]); \
  ub_.x = pk2(Y0[0],Y0[1]);   ub_.y = pk2(Y0[2],Y0[3]); \
  ub_.z = pk2(Y1[0],Y1[1]);   ub_.w = pk2(Y1[2],Y1[3]); \
  int fidx_ = (ROW)*16 + (Q)*4; \
  *(uint4*)&Bm[fidx_ >> 6][68 + (fidx_ & 63)] = ua_; \
  *(uint4*)&Bm[32 + (fidx_ >> 6)][68 + (fidx_ & 63)] = ub_; }
#define WPROW(ROW, V0,V1,V2,V3,V4,V5,V6,V7) \
  WPQ(ROW, V0, V1, 0) WPQ(ROW, V2, V3, 1) WPQ(ROW, V4, V5, 2) WPQ(ROW, V6, V7, 3)

// ---------------- K2: per-(s,o) factorization ----------------
// Reversed space: B = J A J = Wt·Wt^T + I. LDL: B = L~ D L~^T ; S = L~^{-1}.
// logdet_prec = Σ log d_k ; tr(q_cov) = Σ_i ||S row i||²/d_i
// p = S v~ ; qmu~ = S^T (p/d) ; w~ = qmu~ + S^T (eps~/√d) ; w[d] = w~[127-d]
__global__ __launch_bounds__(256, 2) void k2_factor(
    const ushort* __restrict__ phiUT, const float* __restrict__ sqlp,
    const float* __restrict__ smu, const float* __restrict__ eps,
    float* __restrict__ wout, float* __restrict__ klso)
{
  __shared__ __align__(16) float Bm[128][132];
  __shared__ __align__(16) float Tscr[4][2][16][16];
  __shared__ __align__(16) float svec[128];
  __shared__ __align__(16) float smuv[128];
  __shared__ __align__(16) float epsv[128];
  __shared__ __align__(16) float utlv[128];
  __shared__ __align__(16) float dvec[128];
  __shared__ __align__(16) float pvec[128];
  __shared__ __align__(16) float qmuv[128];
  __shared__ __align__(16) float wtv[128];
  float* trv = smuv;   // smuv dead after phase 3
  float* red = svec;   // svec dead after phase 2
  ushort (*Wt)[136] = (ushort (*)[136])&Bm[0][0];

  const int tid  = threadIdx.x;
  const int lane = tid & 63;
  const int wv   = tid >> 6;
  const int s    = blockIdx.x >> 7;
  const int o    = blockIdx.x & 127;

  // phase 1: vectors
  if (tid < 128){
    svec[tid] = sqlp[(o << 7) + tid];
    epsv[tid] = eps[(((size_t)s * 128 + o) << 7) + 127 - tid];
  } else {
    int t2 = tid - 128;
    smuv[t2] = smu[(o << 7) + t2];
  }
  __syncthreads();

  // phase 2: Wt fill (reversed rows, scaled, bf16)
  for (int e = tid * 8; e < 16384; e += 2048){
    int dp = e >> 7, m = e & 127;
    const ushort* srcp = phiUT + (((size_t)s) << 14) + ((size_t)(127 - dp) << 7) + m;
    uint4 raw = *(const uint4*)srcp;
    f32x4 c0 = *(f32x4*)&svec[m];
    f32x4 c1 = *(f32x4*)&svec[m + 4];
    uint4 ov;
    ov.x = pk2(bflo(raw.x)*c0[0], bfhi(raw.x)*c0[1]);
    ov.y = pk2(bflo(raw.y)*c0[2], bfhi(raw.y)*c0[3]);
    ov.z = pk2(bflo(raw.z)*c1[0], bfhi(raw.z)*c1[1]);
    ov.w = pk2(bflo(raw.w)*c1[2], bfhi(raw.w)*c1[3]);
    *(uint4*)&Wt[dp][m] = ov;
  }
  __syncthreads();

  // phase 3: v~ = Wt · (sqrtLp ⊙ mu) — 256 threads (m-halves), batched loads
  {
    float* sA = (float*)Tscr;
    const int i3 = tid & 127, h3 = tid >> 7;
    const int m0 = h3 << 6;
    float acc3 = 0.f;
    #pragma unroll 4
    for (int m = m0; m < m0 + 64; m += 8){
      uint4 raw = *(uint4*)&Wt[i3][m];
      f32x4 u0 = *(f32x4*)&smuv[m];
      f32x4 u1 = *(f32x4*)&smuv[m + 4];
      acc3 += bflo(raw.x) * u0[0] + bfhi(raw.x) * u0[1]
            + bflo(raw.y) * u0[2] + bfhi(raw.y) * u0[3]
            + bflo(raw.z) * u1[0] + bfhi(raw.z) * u1[1]
            + bflo(raw.w) * u1[2] + bfhi(raw.w) * u1[3];
    }
    sA[tid] = acc3;
  }
  __syncthreads();
  if (tid < 128) utlv[tid] = ((float*)Tscr)[tid] + ((float*)Tscr)[tid + 128];
  __syncthreads();

  // phase 4: MFMA Gram
  f32x4 acc[2][8];
  mfma128(Wt, Wt, acc, wv, lane);
  __syncthreads();  // Wt reads complete before overwrite

  // phase 5: Bm = Gram + I (full matrix)
  {
    const int lr = lane & 15, lk = lane >> 4;
    #pragma unroll
    for (int ti = 0; ti < 2; ++ti){
      #pragma unroll
      for (int tj = 0; tj < 8; ++tj){
        int c = tj * 16 + lr;
        #pragma unroll
        for (int q = 0; q < 4; ++q){
          int r = (wv * 2 + ti) * 16 + lk * 4 + q;
          float v = acc[ti][tj][q];
          if (r == c) v += 1.0f;
          Bm[r][c] = v;
        }
      }
    }
  }
  __syncthreads();

  // phase 6: blocked LDL, panel width 32 (unchanged from round 6)
  for (int p = 0; p < 4; ++p){
    const int k0 = p << 5;
    const int nrows = 128 - k0;
    if (wv == 0){
      const int r0 = k0 + lane, r1 = k0 + 64 + lane;
      const bool h0 = lane < nrows;
      const bool h1 = (64 + lane) < nrows;
      const f32x4 z4 = (f32x4){0.f,0.f,0.f,0.f};
      f32x4 ya0,ya1,ya2,ya3,ya4,ya5,ya6,ya7;
      f32x4 yb0,yb1,yb2,yb3,yb4,yb5,yb6,yb7;
      LD(0) LD(1) LD(2) LD(3) LD(4) LD(5) LD(6) LD(7)

      STEP( 0,0,0) STEP( 1,0,1) STEP( 2,0,2) STEP( 3,0,3)
      STEP( 4,1,0) STEP( 5,1,1) STEP( 6,1,2) STEP( 7,1,3)
      STEP( 8,2,0) STEP( 9,2,1) STEP(10,2,2) STEP(11,2,3)
      STEP(12,3,0) STEP(13,3,1) STEP(14,3,2) STEP(15,3,3)
      STEP(16,4,0) STEP(17,4,1) STEP(18,4,2) STEP(19,4,3)
      STEP(20,5,0) STEP(21,5,1) STEP(22,5,2) STEP(23,5,3)
      STEP(24,6,0) STEP(25,6,1) STEP(26,6,2) STEP(27,6,3)
      STEP(28,7,0) STEP(29,7,1) STEP(30,7,2) STEP(31,7,3)

      ST(0) ST(1) ST(2) ST(3) ST(4) ST(5) ST(6) ST(7)
      if (lane < 32) Bm[r0][k0 + lane] = 1.0f;
      if (p < 3){
        if (h0 && lane >= 32) { WPROW(r0, ya0,ya1,ya2,ya3,ya4,ya5,ya6,ya7) }
        if (h1)               { WPROW(r1, yb0,yb1,yb2,yb3,yb4,yb5,yb6,yb7) }
      }
    }
    __syncthreads();
    if (p < 3){
      const int b0 = k0 + 32, n = 128 - b0, ntile = n >> 4;
      const int tiles = (ntile * (ntile + 1)) >> 1;
      const int nextra = ntile >> 1;  // super-diagonal band tiles
      const int ntot = tiles + nextra;
      const int lr = lane & 15, lk = lane >> 4;
      for (int idx = wv; idx < ntot; idx += 4){
        int i0, j0;
        if (idx >= tiles){
          int k = idx - tiles;
          i0 = b0 + (k << 5); j0 = i0 + 16;
        } else {
          int ti = 0;
          while ((ti + 1) * (ti + 2) / 2 <= idx) ++ti;
          int tj = idx - ti * (ti + 1) / 2;
          i0 = b0 + (ti << 4); j0 = b0 + (tj << 4);
        }
        int crow = i0 + (lk << 2), ccol = j0 + lr;
        f32x4 c;
        #pragma unroll
        for (int q = 0; q < 4; ++q) c[q] = Bm[crow + q][ccol];
        int pia = (i0 + lr) * 16 + (lk << 2);
        b16x8 af = *(const b16x8*)&Bm[pia >> 6][68 + (pia & 63)];
        int pib = (j0 + lr) * 16 + (lk << 2);
        b16x8 bfr = *(const b16x8*)&Bm[32 + (pib >> 6)][68 + (pib & 63)];
        c = __builtin_amdgcn_mfma_f32_16x16x32_bf16(af, bfr, c, 0, 0, 0);
        #pragma unroll
        for (int q = 0; q < 4; ++q) Bm[crow + q][ccol] = c[q];
      }
      __syncthreads();
    }
  }

  // zero strict-upper of diag 16x16 blocks (8b full-row dots rely on this)
  for (int e = tid; e < 2048; e += 256){
    int b = e >> 8, r = (e >> 4) & 15, c = e & 15;
    if (c > r) Bm[(b << 4) + r][(b << 4) + c] = 0.0f;
  }

  // phase 8a: invert 16x16 unit-lower diag blocks in place.
  if (wv < 2){
    const int g = lane >> 4, c8 = lane & 15;
    const int ib = ((wv << 2) + g) << 4;
    float Lr[16], x[16];
    #pragma unroll
    for (int r = 0; r < 16; ++r){
      Lr[r] = Bm[ib + r][ib + c8];
      x[r] = (r == c8) ? 1.0f : 0.0f;
    }
    #pragma unroll
    for (int k = 0; k < 15; ++k){
      float xk = x[k];
      #pragma unroll
      for (int r = k + 1; r < 16; ++r){
        float lrk = __shfl(Lr[r], (lane & 48) | k);
        x[r] -= lrk * xk;
      }
    }
    #pragma unroll
    for (int r = 1; r < 16; ++r)
      if (r > c8) Bm[ib + r][ib + c8] = x[r];
  }
  __syncthreads();

  // phase 8b: off-diagonal blocks of S = L~^{-1}, in place — batched f32x4 loads
  {
    const int xr = lane >> 2;
    const int xc = (lane & 3) << 2;
    const f32x4 z4 = (f32x4){0.f,0.f,0.f,0.f};
    for (int I = 1; I < 8; ++I){
      __syncthreads();
      for (int J = wv; J < I; J += 4){
        int slot = J >> 2;
        f32x4 tv = z4;
        for (int K = J; K < I; ++K){
          #pragma unroll
          for (int t = 0; t < 4; ++t){
            f32x4 lv = *(f32x4*)&Bm[(I << 4) + xr][(K << 4) + 4*t];
            f32x4 s0 = *(f32x4*)&Bm[(K << 4) + 4*t + 0][(J << 4) + xc];
            f32x4 s1 = *(f32x4*)&Bm[(K << 4) + 4*t + 1][(J << 4) + xc];
            f32x4 s2 = *(f32x4*)&Bm[(K << 4) + 4*t + 2][(J << 4) + xc];
            f32x4 s3 = *(f32x4*)&Bm[(K << 4) + 4*t + 3][(J << 4) + xc];
            tv += lv[0]*s0 + lv[1]*s1 + lv[2]*s2 + lv[3]*s3;
          }
        }
        *(f32x4*)&Tscr[wv][slot][xr][xc] = tv;
      }
      __syncthreads();
      for (int J = wv; J < I; J += 4){
        int slot = J >> 2;
        // diag row (I,xr) = {S_II lower, 1.0 diag, 0 upper} -> full-row dot == T[xr] + lower terms
        f32x4 x = z4;
        #pragma unroll
        for (int t = 0; t < 4; ++t){
          f32x4 sv = *(f32x4*)&Bm[(I << 4) + xr][(I << 4) + 4*t];
          f32x4 t0 = *(f32x4*)&Tscr[wv][slot][4*t + 0][xc];
          f32x4 t1 = *(f32x4*)&Tscr[wv][slot][4*t + 1][xc];
          f32x4 t2 = *(f32x4*)&Tscr[wv][slot][4*t + 2][xc];
          f32x4 t3 = *(f32x4*)&Tscr[wv][slot][4*t + 3][xc];
          x += sv[0]*t0 + sv[1]*t1 + sv[2]*t2 + sv[3]*t3;
        }
        *(f32x4*)&Bm[(I << 4) + xr][(J << 4) + xc] = -x;
      }
    }
  }
  __syncthreads();

  // phase 9a/9b: row sweeps (trace partials, p = S v~) — 256 threads, j-halves
  {
    float* sA = (float*)Tscr;
    float* sB = sA + 256;
    const int i9 = tid & 127, h9 = tid >> 7;
    const int n4 = i9 >> 2;
    const int lo = h9 ? (n4 >> 1) + 1 : 0;
    const int hi = h9 ? n4 : (n4 >> 1);
    float asq = 0.f, ap = 0.f;
    #pragma unroll 4
    for (int j4 = lo; j4 <= hi; ++j4){
      f32x4 v = *(f32x4*)&Bm[i9][j4 << 2];
      f32x4 uv = *(f32x4*)&utlv[j4 << 2];
      #pragma unroll
      for (int q = 0; q < 4; ++q){
        int j = (j4 << 2) + q;
        bool ok = (j <= i9);
        float sv = ok ? v[q] : 0.f;
        asq += sv * sv;
        ap  += sv * (ok ? uv[q] : 0.f);
      }
    }
    sA[tid] = asq; sB[tid] = ap;
  }
  __syncthreads();
  if (tid < 128){
    float* sA = (float*)Tscr;
    float* sB = sA + 256;
    pvec[tid] = sB[tid] + sB[tid + 128];
    trv[tid]  = (sA[tid] + sA[tid + 128]) / dvec[tid];
  }
  __syncthreads();
  if (tid < 128){
    utlv[tid] = pvec[tid] / dvec[tid];          // g = p / d
    epsv[tid] = epsv[tid] * rsqrtf(dvec[tid]);  // h = eps~ / sqrt(d)
  }
  __syncthreads();
  // phase 9c/9d: column sweeps — 256 threads, i-halves, unrolled
  {
    float* sA = (float*)Tscr;
    float* sB = sA + 256;
    const int j9 = tid & 127, h9 = tid >> 7;
    const int mid = (j9 + 129) >> 1;
    const int lo = h9 ? mid : j9;
    const int hi = h9 ? 128 : mid;
    float aq = 0.f, aw = 0.f;
    #pragma unroll 8
    for (int i = lo; i < hi; ++i){
      float sij = Bm[i][j9];
      aq += sij * utlv[i];
      aw += sij * epsv[i];
    }
    sA[tid] = aq; sB[tid] = aw;
  }
  __syncthreads();
  if (tid < 128){
    float* sA = (float*)Tscr;
    float* sB = sA + 256;
    float aq = sA[tid] + sA[tid + 128];
    float aw = sB[tid] + sB[tid + 128];
    qmuv[tid] = aq;
    wtv[tid] = aq + aw;
  }
  __syncthreads();
  // phase 9e: reductions + kl; 9f: write w
  float ra = 0.f, rb = 0.f, rc = 0.f;
  if (tid < 128){
    ra = trv[tid];
    float q = qmuv[tid];
    rb = q * q;
    rc = logf(dvec[tid]);
  }
  #pragma unroll
  for (int off = 32; off > 0; off >>= 1){
    ra += __shfl_xor(ra, off);
    rb += __shfl_xor(rb, off);
    rc += __shfl_xor(rc, off);
  }
  if (lane == 0){
    red[wv * 4 + 0] = ra; red[wv * 4 + 1] = rb; red[wv * 4 + 2] = rc;
  }
  __syncthreads();
  if (tid == 0){
    float tr = red[0] + red[4] + red[8]  + red[12];
    float q2 = red[1] + red[5] + red[9]  + red[13];
    float ld = red[2] + red[6] + red[10] + red[14];
    klso[(s << 7) + o] = 0.5f * (tr + q2 - 128.0f + ld);
  }
  if (tid < 128)
    wout[(((size_t)(s << 7) + o) << 7) + tid] = wtv[127 - tid];
}

// ---------------- K3: F_out / U_out GEMMs ----------------
__global__ __launch_bounds__(256, 2) void k3_outs(
    const float* __restrict__ F, const float* __restrict__ U,
    const float* __restrict__ wbuf, float* __restrict__ out)
{
  __shared__ __align__(16) ushort Ab[128][136];
  __shared__ __align__(16) ushort Wb[128][136];
  const int tid = threadIdx.x;
  const int lane = tid & 63, wv = tid >> 6;
  const int bid = blockIdx.x;
  const float* src;
  float* dst;
  int s;
  if (bid < 512){
    s = bid >> 5;
    int t = bid & 31;
    size_t off = (((size_t)s * 4096) + (size_t)t * 128) * 128;
    src = F + off;
    dst = out + off;
  } else {
    s = bid - 512;
    src = U + ((size_t)s << 14);
    dst = out + (size_t)8388608 + ((size_t)s << 14);
  }
  for (int e = tid * 4; e < 16384; e += 1024){
    f32x4 v = *(const f32x4*)&src[e];
    uint2 pv; pv.x = pk2(fmaxf(v[0],0.f), fmaxf(v[1],0.f));
    pv.y = pk2(fmaxf(v[2],0.f), fmaxf(v[3],0.f));
    *(uint2*)&Ab[e >> 7][e & 127] = pv;
  }
  const float* wsrc = wbuf + ((size_t)s << 14);
  for (int e = tid * 4; e < 16384; e += 1024){
    f32x4 v = *(const f32x4*)&wsrc[e];
    uint2 pv; pv.x = pk2(v[0], v[1]); pv.y = pk2(v[2], v[3]);
    *(uint2*)&Wb[e >> 7][e & 127] = pv;
  }
  __syncthreads();
  f32x4 acc[2][8];
  mfma128(Ab, Wb, acc, wv, lane);
  const int lr = lane & 15, lk = lane >> 4;
  #pragma unroll
  for (int ti = 0; ti < 2; ++ti){
    #pragma unroll
    for (int tj = 0; tj < 8; ++tj){
      int c = tj * 16 + lr;
      #pragma unroll
      for (int q = 0; q < 4; ++q){
        int r = (wv * 2 + ti) * 16 + lk * 4 + q;
        dst[(size_t)r * 128 + c] = acc[ti][tj][q];
      }
    }
  }
}

// ---------------- K4: kl reduction ----------------
__global__ void k4_klred(const float* __restrict__ klso, float* __restrict__ klout){
  __shared__ float sums[16][17];
  const int t = threadIdx.x;
  int s = t >> 4, ch = t & 15;
  float a = 0.f;
  for (int q = 0; q < 8; ++q) a += klso[(s << 7) + ch * 8 + q];
  sums[s][ch] = a;
  __syncthreads();
  if (t < 16){
    float r = 0.f;
    for (int c = 0; c < 16; ++c) r += sums[t][c];
    klout[t] = r;
  }
}

extern "C" void kernel_launch(void* const* d_in, const int* in_sizes, int n_in,
                              void* d_out, int out_size, void* d_ws, size_t ws_size,
                              hipStream_t stream) {
  const float* F   = (const float*)d_in[0];
  const float* U   = (const float*)d_in[1];
  const float* mu  = (const float*)d_in[2];
  const float* lp  = (const float*)d_in[3];
  const float* eps = (const float*)d_in[4];
  float* out = (float*)d_out;
  char* ws = (char*)d_ws;
  ushort* phiUT = (ushort*)(ws + PHIUT_OFF);
  float* sqlp = (float*)(ws + SQLP_OFF);
  float* smu  = (float*)(ws + SMU_OFF);
  float* wbuf = (float*)(ws + WBUF_OFF);
  float* klso = (float*)(ws + KLSO_OFF);

  k0_prep<<<dim3(80), dim3(256), 0, stream>>>(U, mu, lp, phiUT, sqlp, smu);
  k2_factor<<<dim3(2048), dim3(256), 0, stream>>>(phiUT, sqlp, smu, eps, wbuf, klso);
  k3_outs<<<dim3(528), dim3(256), 0, stream>>>(F, U, wbuf, out);
  k4_klred<<<dim3(1), dim3(256), 0, stream>>>(klso, out + 8650752);
}